// Round 2
// baseline (6340.952 us; speedup 1.0000x reference)
//
#include <hip/hip_runtime.h>
#include <hip/hip_bf16.h>
#include <hip/hip_cooperative_groups.h>
#include <math.h>

namespace cg = cooperative_groups;

#define B 256
#define S 128
#define I_DIM 512
#define H 1024
#define C 10
#define FH 4096
#define WROW 1536

#define SMEM_W_BYTES (64 * 2048)          // 64 n-rows x 1024 k x bf16, swizzled
#define SMEM_TOTAL   (SMEM_W_BYTES + 4096) // + 4 waves x 1KB h-staging

typedef float f32x4 __attribute__((ext_vector_type(4)));
typedef __bf16 bf16x8 __attribute__((ext_vector_type(8)));

__device__ __forceinline__ unsigned short f2bf(float f) {
    union { float f; unsigned u; } a; a.f = f;
    return (unsigned short)((a.u + 0x7fffu + ((a.u >> 16) & 1u)) >> 16);
}
__device__ __forceinline__ float sigf(float v) { return 1.0f / (1.0f + __expf(-v)); }
__device__ __forceinline__ float tanh_fast(float v) { return 1.0f - 2.0f / (1.0f + __expf(2.0f * v)); }

// projP[d][jt][v][jj][g] = embed[v] . Wx_d[g*1024 + jt*16 + jj] + b_d[...]
__global__ void proj_kernel(const float* __restrict__ embed,
                            const float* __restrict__ fwd_W,
                            const float* __restrict__ fwd_b,
                            const float* __restrict__ bwd_W,
                            const float* __restrict__ bwd_b,
                            float* __restrict__ projP) {
    __shared__ float wrows[16][516];
    int d  = blockIdx.x >> 8;
    int nc = blockIdx.x & 255;
    int n0 = nc * 16;
    const float* W    = d ? bwd_W : fwd_W;
    const float* bias = d ? bwd_b : fwd_b;
    int tid = threadIdx.x;
    for (int idx = tid; idx < 16 * 512; idx += 256) {
        int r = idx >> 9, k = idx & 511;
        wrows[r][k] = W[(n0 + r) * WROW + k];
    }
    __syncthreads();
    for (int o = tid; o < 128 * 16; o += 256) {
        int v = o >> 4, r = o & 15;
        const float* er = embed + v * I_DIM;
        float s = bias[n0 + r];
        for (int k = 0; k < I_DIM; k++) s += er[k] * wrows[r][k];
        int n = n0 + r;
        int g = n >> 10, jrem = n & 1023;
        int jtl = jrem >> 4, jj = jrem & 15;
        projP[(((size_t)(d * 64 + jtl)) * 128 + v) * 64 + jj * 4 + g] = s;
    }
}

// Persistent bi-LSTM: 256 blocks (1/CU), 256 threads (4 waves).
// block = (d, bh, jt): d=dir, bh=batch-half (128 b), jt=j-tile (16 j => 64 gate-interleaved n).
// wave (wr,wc): wr=b-half (64 b), wc=n-half (32 n).
__global__ __launch_bounds__(256) void bilstm_persistent(
        const int* __restrict__ x,
        const float* __restrict__ fwd_W,
        const float* __restrict__ bwd_W,
        const float* __restrict__ projP,
        const float* __restrict__ p_w,
        const float* __restrict__ p_b,
        __hip_bfloat16* __restrict__ hbuf,  // [2 buf][2 d][256 b][1024 j]
        float* __restrict__ hf,             // [2 d][256 b][1024 j]
        float* __restrict__ out) {
    extern __shared__ char smem[];
    char* wb = smem;                                  // swizzled bf16 W [64][1024]
    unsigned short* hstage = (unsigned short*)(smem + SMEM_W_BYTES);

    cg::grid_group grid = cg::this_grid();

    const int bid = blockIdx.x;
    const int d  = bid >> 7;
    const int bh = (bid >> 6) & 1;
    const int jt = bid & 63;
    const int tid = threadIdx.x;
    const int wid = tid >> 6, lane = tid & 63;
    const int wc = wid & 1, wr = wid >> 1;
    const int l15 = lane & 15, l4 = lane >> 4;

    const float* W = d ? bwd_W : fwd_W;

    // ---- load this block's Wh slice into LDS as bf16, XOR-swizzled ----
    // n_local = jj*4 + g  <->  W row g*1024 + jt*16 + jj, cols 512..1535
    for (int n = 0; n < 64; n++) {
        int g = n & 3, jj = n >> 2;
        const float* src = W + (size_t)(g * 1024 + jt * 16 + jj) * WROW + I_DIM + tid * 4;
        f32x4 v = *(const f32x4*)src;
        ushort4 pk = make_ushort4(f2bf(v[0]), f2bf(v[1]), f2bf(v[2]), f2bf(v[3]));
        int off = n * 2048 + ((tid * 8) ^ ((n & 7) << 4));
        *(ushort4*)(wb + off) = pk;
    }
    __syncthreads();

    // per-lane constant addressing
    int abase[2], aswz[2];
#pragma unroll
    for (int i2 = 0; i2 < 2; i2++) {
        int row = wc * 32 + i2 * 16 + l15;
        abase[i2] = row * 2048;
        aswz[i2]  = (row & 7) << 4;
    }
    size_t hrow[4];
    int bglob[4];
#pragma unroll
    for (int jf = 0; jf < 4; jf++) {
        bglob[jf] = bh * 128 + wr * 64 + jf * 16 + l15;
        hrow[jf] = (size_t)bglob[jf] * H;
    }
    const size_t dHB = (size_t)d * B * H;
    const float* pbase = projP + ((size_t)(d * 64 + jt)) * 128 * 64;
    unsigned short* hst = hstage + wid * 512;

    float cst[2][4];
#pragma unroll
    for (int i2 = 0; i2 < 2; i2++)
#pragma unroll
        for (int jf = 0; jf < 4; jf++) cst[i2][jf] = 0.0f;

    for (int t = 0; t < S; t++) {
        const int tt = d ? (S - 1 - t) : t;

        // gather x then proj (latency hidden under GEMM)
        int vv[4];
#pragma unroll
        for (int jf = 0; jf < 4; jf++) vv[jf] = x[bglob[jf] * S + tt];
        f32x4 pj[2][4];
#pragma unroll
        for (int i2 = 0; i2 < 2; i2++) {
            int jj = wc * 8 + i2 * 4 + l4;
#pragma unroll
            for (int jf = 0; jf < 4; jf++)
                pj[i2][jf] = *(const f32x4*)(pbase + (size_t)vv[jf] * 64 + jj * 4);
        }

        f32x4 acc[2][4];
#pragma unroll
        for (int i2 = 0; i2 < 2; i2++)
#pragma unroll
            for (int jf = 0; jf < 4; jf++) acc[i2][jf] = (f32x4){0.f, 0.f, 0.f, 0.f};

        if (t > 0) {
            const __hip_bfloat16* hr = hbuf + ((size_t)(t & 1) * 2 * B * H) + dHB;
            bf16x8 af[2][2], bfr[2][4];
            // preload k-chunk 0
            {
                int kof = (l4 * 8) * 2;
#pragma unroll
                for (int i2 = 0; i2 < 2; i2++)
                    af[0][i2] = *(const bf16x8*)(wb + abase[i2] + (kof ^ aswz[i2]));
#pragma unroll
                for (int jf = 0; jf < 4; jf++)
                    bfr[0][jf] = *(const bf16x8*)(hr + hrow[jf] + l4 * 8);
            }
#pragma unroll
            for (int kk = 0; kk < 32; kk++) {
                const int cur = kk & 1, nxt = cur ^ 1;
                if (kk < 31) {
                    int kof = ((kk + 1) * 32 + l4 * 8) * 2;
#pragma unroll
                    for (int i2 = 0; i2 < 2; i2++)
                        af[nxt][i2] = *(const bf16x8*)(wb + abase[i2] + (kof ^ aswz[i2]));
#pragma unroll
                    for (int jf = 0; jf < 4; jf++)
                        bfr[nxt][jf] = *(const bf16x8*)(hr + hrow[jf] + (kk + 1) * 32 + l4 * 8);
                }
#pragma unroll
                for (int i2 = 0; i2 < 2; i2++)
#pragma unroll
                    for (int jf = 0; jf < 4; jf++)
                        acc[i2][jf] = __builtin_amdgcn_mfma_f32_16x16x32_bf16(
                            af[cur][i2], bfr[cur][jf], acc[i2][jf], 0, 0, 0);
            }
        }

        // gates: lane holds all 4 gates of (b = bglob[jf], jj) in acc[i2][jf][0..3]
#pragma unroll
        for (int i2 = 0; i2 < 2; i2++) {
            int jjl = i2 * 4 + l4;  // local 0..7 within wave's 8 jj
#pragma unroll
            for (int jf = 0; jf < 4; jf++) {
                float zg = acc[i2][jf][0] + pj[i2][jf][0];
                float zi = acc[i2][jf][1] + pj[i2][jf][1];
                float zf = acc[i2][jf][2] + pj[i2][jf][2];
                float zo = acc[i2][jf][3] + pj[i2][jf][3];
                float gg = tanh_fast(zg);
                float ii = sigf(zi);
                float ff = sigf(zf);
                float oo = sigf(zo);
                float cn = gg * ii + cst[i2][jf] * ff;
                cst[i2][jf] = cn;
                float hn = tanh_fast(cn) * oo;
                hst[(jf * 16 + l15) * 8 + jjl] = f2bf(hn);
                if (t == S - 1)
                    hf[dHB + hrow[jf] + jt * 16 + wc * 8 + jjl] = hn;
            }
        }

        // wave-local LDS -> coalesced 16B global store of h
        {
            uint4 hv = *(const uint4*)((const char*)hst + lane * 16);
            __hip_bfloat16* hw = hbuf + ((size_t)((t + 1) & 1) * 2 * B * H) + dHB;
            *(uint4*)(hw + (size_t)(bh * 128 + wr * 64 + lane) * H + jt * 16 + wc * 8) = hv;
        }

        grid.sync();
    }

    // ---- head: block b computes out[b][0..9] with wave 0 ----
    if (tid < 64) {
        int b = bid;
        float part[C];
#pragma unroll
        for (int cc = 0; cc < C; cc++) part[cc] = 0.0f;
        for (int jj = tid; jj < 2 * H; jj += 64) {
            float hv = (jj < H) ? hf[(size_t)b * H + jj]
                                : hf[(size_t)B * H + (size_t)b * H + jj - H];
#pragma unroll
            for (int cc = 0; cc < C; cc++) part[cc] += hv * p_w[cc * 2 * H + jj];
        }
#pragma unroll
        for (int cc = 0; cc < C; cc++) {
            float v = part[cc];
            for (int off = 32; off; off >>= 1) v += __shfl_down(v, off);
            part[cc] = v;
        }
        if (tid == 0) {
            float lg[C];
            float m = -1e30f;
            for (int cc = 0; cc < C; cc++) {
                lg[cc] = part[cc] + p_b[cc];
                m = fmaxf(m, lg[cc]);
            }
            float s = 0.0f;
            for (int cc = 0; cc < C; cc++) s += expf(lg[cc] - m);
            float lse = logf(s) + m;
            for (int cc = 0; cc < C; cc++) out[b * C + cc] = lg[cc] - lse;
        }
    }
}

extern "C" void kernel_launch(void* const* d_in, const int* in_sizes, int n_in,
                              void* d_out, int out_size, void* d_ws, size_t ws_size,
                              hipStream_t stream) {
    const int*   x     = (const int*)d_in[0];
    const float* embed = (const float*)d_in[1];
    const float* fwd_W = (const float*)d_in[2];
    const float* fwd_b = (const float*)d_in[3];
    const float* bwd_W = (const float*)d_in[4];
    const float* bwd_b = (const float*)d_in[5];
    const float* p_w   = (const float*)d_in[6];
    const float* p_b   = (const float*)d_in[7];
    float* outp = (float*)d_out;

    char* ws = (char*)d_ws;
    float* projP = (float*)ws;                 ws += (size_t)2 * 64 * 128 * 64 * 4;  // 4 MB
    __hip_bfloat16* hbuf = (__hip_bfloat16*)ws; ws += (size_t)2 * 2 * B * H * 2;     // 2 MB
    float* hfb = (float*)ws;                    ws += (size_t)2 * B * H * 4;         // 2 MB

    hipLaunchKernelGGL(proj_kernel, dim3(512), dim3(256), 0, stream,
                       embed, fwd_W, fwd_b, bwd_W, bwd_b, projP);

    hipFuncSetAttribute((const void*)bilstm_persistent,
                        hipFuncAttributeMaxDynamicSharedMemorySize, SMEM_TOTAL);

    void* args[] = {(void*)&x, (void*)&fwd_W, (void*)&bwd_W, (void*)&projP,
                    (void*)&p_w, (void*)&p_b, (void*)&hbuf, (void*)&hfb, (void*)&outp};
    hipLaunchCooperativeKernel((void*)bilstm_persistent, dim3(256), dim3(256),
                               args, SMEM_TOTAL, stream);
}